// Round 13
// baseline (7791.725 us; speedup 1.0000x reference)
//
#include <hip/hip_runtime.h>
#include <hip/hip_fp16.h>
#include <math.h>

#define BB 32
#define LAV 256
#define LCV 256
#define DV 300
#define HV 256
#define G3 768   // 3*H

typedef _Float16 f16x2 __attribute__((ext_vector_type(2)));
union F4H8 { float4 f4; f16x2 h2[4]; };
union U2H4 { uint2 u2; f16x2 h2[2]; };

// ---------- fast math helpers ----------
static __device__ __forceinline__ float rcp_(float x) { return __builtin_amdgcn_rcpf(x); }
static __device__ __forceinline__ float sigm(float x) { return rcp_(1.f + __expf(-x)); }
static __device__ __forceinline__ float tanh_(float x) { return 1.f - 2.f * rcp_(1.f + __expf(2.f * x)); }

// ---------- weight packing ----------
// c0: WT_a  [300][768] = W_ih_a^T (fp32)
// c1: WT_cx [300][768] = W_ih_c[:,:300]^T (fp32)
// c2: WhaRH half anchor reg slice [768 t][64 ii][2 e]: W_hh_a[t][2*ii+e]
// c3: WhaSH half anchor stream    [32 i2][768 j][2 s][2 e]: k2=64+2*i2+s, W_hh_a[j][2*k2+e]
// c4: Wq4   half [32 kq][256 m][4 c][2 e]  = Wq[8kq+2c+e][m]          (quad-k pack)
// c5: Wrz4  half [32 kq][512 j][4 c][2 e]  = W_hh_c[j][8kq+2c+e]      (rz hidden only)
// c6: Wn4   half [32 kq][256 j][4 c][2 e]  = W_hh_c[512+j][8kq+2c+e]  (n hidden only)
// c7: WcxCT fp32 [256 k][768 j] = W_ih_c[j][300+k]   (B operand for P gemm)
__global__ void prep_pack(const float* __restrict__ W_ih_a, const float* __restrict__ W_ih_c,
                          const float* __restrict__ W_hh_a, const float* __restrict__ W_hh_c,
                          const float* __restrict__ Wq,
                          float* __restrict__ WT_a, float* __restrict__ WT_cx,
                          __half* __restrict__ WhaRH, __half* __restrict__ WhaSH,
                          __half* __restrict__ Wq4, __half* __restrict__ Wrz4,
                          __half* __restrict__ Wn4, float* __restrict__ WcxCT)
{
    int i = blockIdx.x * 256 + threadIdx.x;
    switch (blockIdx.y) {
    case 0: if (i < 230400) { int k = i / 768, n = i % 768; WT_a[i] = W_ih_a[n * 300 + k]; } break;
    case 1: if (i < 230400) { int k = i / 768, n = i % 768; WT_cx[i] = W_ih_c[n * 556 + k]; } break;
    case 2: if (i < 98304) { int e = i & 1, r = i >> 1, ii = r & 63, j = r >> 6;
            WhaRH[i] = __float2half(W_hh_a[j * 256 + 2 * ii + e]); } break;
    case 3: if (i < 98304) { int e = i & 1, s = (i >> 1) & 1, r = i >> 2, j = r % 768, i2 = r / 768;
            int k = 2 * (64 + 2 * i2 + s) + e;
            WhaSH[i] = __float2half(W_hh_a[j * 256 + k]); } break;
    case 4: if (i < 65536) { int e = i & 1, c = (i >> 1) & 3, r = i >> 3, m = r & 255, kq = r >> 8;
            int k = 8 * kq + 2 * c + e;
            Wq4[i] = __float2half(Wq[k * 256 + m]); } break;
    case 5: if (i < 131072) { int e = i & 1, c = (i >> 1) & 3, r = i >> 3, j = r & 511, kq = r >> 9;
            int k = 8 * kq + 2 * c + e;
            Wrz4[i] = __float2half(W_hh_c[j * 256 + k]); } break;
    case 6: if (i < 65536) { int e = i & 1, c = (i >> 1) & 3, r = i >> 3, j = r & 255, kq = r >> 8;
            int k = 8 * kq + 2 * c + e;
            Wn4[i] = __float2half(W_hh_c[(512 + j) * 256 + k]); } break;
    case 7: if (i < 196608) { int k = i / 768, j = i % 768;
            WcxCT[i] = W_ih_c[j * 556 + 300 + k]; } break;
    }
}

// ---------- tiled fp32 GEMM ----------
// MODE 0: Cout[m*N+n] = acc + bias[n]                           (GI precompute)
// MODE 1: T4 half[b][hq 64][l2 128][4 c][2 e] = tanh(keys)      (h=4hq+c, l=2*l2+e)
// MODE 2: P4 half[lq 1024][768 col][4 c][2 e] = P               (l=8lq+2c+e global row)
template <int MODE>
__global__ __launch_bounds__(256) void gemm_tile(
    const float* __restrict__ X, const int* __restrict__ gidx, int ldx,
    const float* __restrict__ Wt, int K, int Nn,
    const float* __restrict__ bias, float* __restrict__ Cout)
{
    __shared__ __align__(16) float As[32][68];
    __shared__ __align__(16) float Bs[32][68];
    __shared__ int toks[64];
    int tid = threadIdx.x;
    int m0 = blockIdx.x * 64, n0 = blockIdx.y * 64;
    if (tid < 64) {
        int m = m0 + tid;
        if (gidx) { int t = m >> 5, b = m & 31; toks[tid] = gidx[b * LAV + t]; }
        else toks[tid] = m;
    }
    __syncthreads();
    float acc[4][4] = {};
    int tx = tid & 15, ty = tid >> 4;
    for (int k0 = 0; k0 < K; k0 += 32) {
        {
            int r = tid >> 2, cc = (tid & 3) * 8;
            const float* src = X + (size_t)toks[r] * ldx + k0 + cc;
            float4 v0 = {0.f,0.f,0.f,0.f}, v1 = {0.f,0.f,0.f,0.f};
            if (k0 + cc + 3 < K) v0 = *(const float4*)src;
            if (k0 + cc + 7 < K) v1 = *(const float4*)(src + 4);
            As[cc+0][r]=v0.x; As[cc+1][r]=v0.y; As[cc+2][r]=v0.z; As[cc+3][r]=v0.w;
            As[cc+4][r]=v1.x; As[cc+5][r]=v1.y; As[cc+6][r]=v1.z; As[cc+7][r]=v1.w;
        }
        {
            int kr = tid >> 4, c4 = (tid & 15) * 4;
            #pragma unroll
            for (int p = 0; p < 2; ++p) {
                float4 v = {0.f,0.f,0.f,0.f};
                int kg = k0 + kr + p * 16;
                if (kg < K) v = *(const float4*)(Wt + (size_t)kg * Nn + n0 + c4);
                *(float4*)&Bs[kr + p * 16][c4] = v;
            }
        }
        __syncthreads();
        #pragma unroll 8
        for (int kk = 0; kk < 32; ++kk) {
            float4 a4 = *(const float4*)&As[kk][ty * 4];
            float4 b4 = *(const float4*)&Bs[kk][tx * 4];
            acc[0][0]=fmaf(a4.x,b4.x,acc[0][0]); acc[0][1]=fmaf(a4.x,b4.y,acc[0][1]);
            acc[0][2]=fmaf(a4.x,b4.z,acc[0][2]); acc[0][3]=fmaf(a4.x,b4.w,acc[0][3]);
            acc[1][0]=fmaf(a4.y,b4.x,acc[1][0]); acc[1][1]=fmaf(a4.y,b4.y,acc[1][1]);
            acc[1][2]=fmaf(a4.y,b4.z,acc[1][2]); acc[1][3]=fmaf(a4.y,b4.w,acc[1][3]);
            acc[2][0]=fmaf(a4.z,b4.x,acc[2][0]); acc[2][1]=fmaf(a4.z,b4.y,acc[2][1]);
            acc[2][2]=fmaf(a4.z,b4.z,acc[2][2]); acc[2][3]=fmaf(a4.z,b4.w,acc[2][3]);
            acc[3][0]=fmaf(a4.w,b4.x,acc[3][0]); acc[3][1]=fmaf(a4.w,b4.y,acc[3][1]);
            acc[3][2]=fmaf(a4.w,b4.z,acc[3][2]); acc[3][3]=fmaf(a4.w,b4.w,acc[3][3]);
        }
        __syncthreads();
    }
    if (MODE == 0) {
        float4 bz = *(const float4*)&bias[n0 + tx * 4];
        #pragma unroll
        for (int i = 0; i < 4; ++i) {
            int m = m0 + ty * 4 + i;
            float4 o = { acc[i][0] + bz.x, acc[i][1] + bz.y, acc[i][2] + bz.z, acc[i][3] + bz.w };
            *(float4*)&Cout[(size_t)m * Nn + n0 + tx * 4] = o;
        }
    } else if (MODE == 1) {
        int b_ = m0 >> 8;
        int l0 = (m0 & 255) + ty * 4;
        f16x2* T4 = (f16x2*)Cout;
        #pragma unroll
        for (int j = 0; j < 4; ++j) {
            int h = n0 + tx * 4 + j;
            size_t base = (((size_t)(b_ * 64 + (h >> 2)) * 128) + (l0 >> 1)) * 4 + (h & 3);
            f16x2 v01 = { (_Float16)tanh_(acc[0][j]), (_Float16)tanh_(acc[1][j]) };
            f16x2 v23 = { (_Float16)tanh_(acc[2][j]), (_Float16)tanh_(acc[3][j]) };
            T4[base] = v01;
            T4[base + 4] = v23;
        }
    } else {
        int l0 = m0 + ty * 4;           // global row (b*256 + l)
        f16x2* P4 = (f16x2*)Cout;
        #pragma unroll
        for (int j = 0; j < 4; ++j) {
            int col = n0 + tx * 4 + j;
            size_t base = ((size_t)(l0 >> 3) * 768 + col) * 4 + ((l0 >> 1) & 3);
            f16x2 v01 = { (_Float16)acc[0][j], (_Float16)acc[1][j] };
            f16x2 v23 = { (_Float16)acc[2][j], (_Float16)acc[3][j] };
            P4[base] = v01;
            P4[base + 1] = v23;
        }
    }
}

// ---------- anchor GRU: one WG/batch, fp16 (reg slice + stream) — R5/R8-proven ----------
__global__ __launch_bounds__(768) void anchor_rnn(
    const float* __restrict__ GI, const int* __restrict__ lens,
    const float* __restrict__ bhh, const __half* __restrict__ WhaRH,
    const __half* __restrict__ WhaSH,
    float* __restrict__ AO, __half* __restrict__ AOH,
    float* __restrict__ hid, float* __restrict__ outp)
{
    __shared__ float gh[768];
    __shared__ __align__(16) float hs[256];
    __shared__ __align__(16) f16x2 hx2[128];
    __shared__ float bhhS[768];
    int bid = blockIdx.x, tid = threadIdx.x;
    int len = lens[bid];

    f16x2 wreg[64];
    {
        const float4* s = (const float4*)WhaRH + (size_t)tid * 16;
        #pragma unroll
        for (int u = 0; u < 16; ++u) {
            F4H8 c; c.f4 = s[u];
            wreg[4*u+0] = c.h2[0]; wreg[4*u+1] = c.h2[1];
            wreg[4*u+2] = c.h2[2]; wreg[4*u+3] = c.h2[3];
        }
    }
    if (tid < 256) hs[tid] = 0.f;
    if (tid < 128) { f16x2 z = {(_Float16)0.f, (_Float16)0.f}; hx2[tid] = z; }
    bhhS[tid] = bhh[tid];
    float sum = 0.f;
    __syncthreads();

    for (int t = 0; t < LAV; ++t) {
        { // gh[j] = W_hh_a[j,:] @ h (+ b_hh): k2 0..63 from regs + k2 64..127 streamed
            float a0=0.f,a1=0.f,a2=0.f,a3=0.f;
            const float4* xb = (const float4*)hx2;
            #pragma unroll
            for (int u = 0; u < 16; ++u) {
                F4H8 xv; xv.f4 = xb[u];
                a0 = __builtin_amdgcn_fdot2(wreg[4*u+0], xv.h2[0], a0, false);
                a1 = __builtin_amdgcn_fdot2(wreg[4*u+1], xv.h2[1], a1, false);
                a2 = __builtin_amdgcn_fdot2(wreg[4*u+2], xv.h2[2], a2, false);
                a3 = __builtin_amdgcn_fdot2(wreg[4*u+3], xv.h2[3], a3, false);
            }
            const uint2* wsp = (const uint2*)WhaSH + tid;
            float b0=0.f,b1=0.f;
            #pragma unroll
            for (int i2 = 0; i2 < 32; ++i2) {   // full 32 i2 slots (k2 64..127)
                U2H4 w; w.u2 = wsp[(size_t)i2 * 768];
                U2H4 xx; xx.u2 = *(const uint2*)&hx2[64 + 2 * i2];
                b0 = __builtin_amdgcn_fdot2(w.h2[0], xx.h2[0], b0, false);
                b1 = __builtin_amdgcn_fdot2(w.h2[1], xx.h2[1], b1, false);
            }
            gh[tid] = ((a0 + a1) + (a2 + a3)) + (b0 + b1) + bhhS[tid];
        }
        __syncthreads();
        if (tid < 256) {
            const float* gi = GI + ((size_t)t * BB + bid) * G3;
            float r = sigm(gi[tid] + gh[tid]);
            float z = sigm(gi[256 + tid] + gh[256 + tid]);
            float n = tanh_(fmaf(r, gh[512 + tid], gi[512 + tid]));
            float hk = hs[tid];
            float hn = (1.f - z) * n + z * hk;
            bool valid = (t < len);
            float hnew = valid ? hn : hk;
            hs[tid] = hnew;
            float ov = valid ? hn : 0.f;
            AO[((size_t)bid * LAV + t) * HV + tid] = ov;
            AOH[((size_t)bid * LAV + t) * HV + tid] = __float2half(ov);
            sum += ov;
            float other = __shfl_xor(hnew, 1, 64);
            if (!(tid & 1)) {
                f16x2 v = { (_Float16)hnew, (_Float16)other };
                hx2[tid >> 1] = v;
            }
        }
        __syncthreads();
    }
    if (tid < 256) {
        outp[bid * HV + tid] = sum / (float)len;
        hid[bid * HV + tid] = hs[tid];
    }
}

// ---------- candidate GRU + attention: one WG/batch ----------
// Wn in LDS (step-invariant); T prefetched in A; P partially prefetched in C;
// fused per-wave flash softmax (5 barriers/step).
__global__ __launch_bounds__(1024, 4) void cand_rnn(
    const float* __restrict__ GI, const int* __restrict__ lens,
    const float* __restrict__ bhh, const __half* __restrict__ Wrz4,
    const __half* __restrict__ Wn4, const __half* __restrict__ Wq4,
    const float* __restrict__ v_att, const __half* __restrict__ P4H,
    const __half* __restrict__ T4H, const float* __restrict__ hid,
    float* __restrict__ outp)
{
    __shared__ __align__(16) __half WnS[65536];    // 128 KB, loaded once
    __shared__ __align__(16) f16x2 x2[128];        // h pairs (read as float4 quads)
    __shared__ __align__(16) float hs[256];
    __shared__ __align__(16) float2 tqv[256];      // {tq, v*tq}
    __shared__ float vls[256];
    __shared__ __align__(16) __half attnH[256];    // per-wave exp(s-m_w), fp16
    __shared__ __align__(16) float redBig[3072];   // scores (C, 2048) -> gateC4 (E', 3072)
    __shared__ __align__(16) float redRZh[512];
    __shared__ __align__(16) float redNh[256];
    __shared__ float bhhS[768];
    __shared__ float wred[8];                      // {m_w, S_w} x 4 waves

    int tid = threadIdx.x;
    int b = blockIdx.x;
    int len = lens[b];

    const float4* Wq4f  = (const float4*)Wq4;
    const float4* Wrz4f = (const float4*)Wrz4;
    const float4* T4f   = (const float4*)T4H + (size_t)b * 64 * 128;
    const float4* P4f   = (const float4*)P4H + (size_t)b * 32 * 768;
    const float4* x4    = (const float4*)x2;
    const float4* at4   = (const float4*)attnH;
    const float4* WnSf  = (const float4*)WnS;

    { // stage Wn into LDS once (8192 float4)
        const float4* s = (const float4*)Wn4;
        float4* d = (float4*)WnS;
        #pragma unroll
        for (int u = 0; u < 8; ++u) d[u * 1024 + tid] = s[u * 1024 + tid];
    }
    if (tid < 256) { hs[tid] = hid[b * HV + tid]; vls[tid] = v_att[tid]; }
    if (tid < 768) bhhS[tid] = bhh[tid];
    __syncthreads();
    if (tid < 128) {
        f16x2 v = { (_Float16)hs[2 * tid], (_Float16)hs[2 * tid + 1] };
        x2[tid] = v;
    }
    __syncthreads();

    float csum = 0.f;
    int l2c = tid & 127, hgc = tid >> 7;   // C-phase role indices
    const float4* Tb = T4f + (size_t)(hgc * 8) * 128 + l2c;

    for (int t = 0; t < LCV; ++t) {
        float gir = 0.f, giz = 0.f, gin = 0.f;
        // ---- T prefetch for phase C (completes under phase A) ----
        F4H8 treg0, treg1, treg2, treg3, treg4, treg5, treg6, treg7;
        treg0.f4 = Tb[0 * 128]; treg1.f4 = Tb[1 * 128];
        treg2.f4 = Tb[2 * 128]; treg3.f4 = Tb[3 * 128];
        treg4.f4 = Tb[4 * 128]; treg5.f4 = Tb[5 * 128];
        treg6.f4 = Tb[6 * 128]; treg7.f4 = Tb[7 * 128];
        // ---- A: full-output role split ----
        if (tid < 256) {
            const float* gi = GI + ((size_t)t * BB + b) * G3 + tid;
            gir = gi[0]; giz = gi[256]; gin = gi[512];
            int m = tid;
            float a0 = 0.f, a1 = 0.f, a2 = 0.f, a3 = 0.f;
            #pragma unroll 8
            for (int kq = 0; kq < 32; ++kq) {
                F4H8 w; w.f4 = Wq4f[(size_t)kq * 256 + m];
                F4H8 xx; xx.f4 = x4[kq];
                a0 = __builtin_amdgcn_fdot2(w.h2[0], xx.h2[0], a0, false);
                a1 = __builtin_amdgcn_fdot2(w.h2[1], xx.h2[1], a1, false);
                a2 = __builtin_amdgcn_fdot2(w.h2[2], xx.h2[2], a2, false);
                a3 = __builtin_amdgcn_fdot2(w.h2[3], xx.h2[3], a3, false);
            }
            float tq = tanh_((a0 + a1) + (a2 + a3));
            tqv[m] = make_float2(tq, vls[m] * tq);
        } else if (tid < 768) {
            int j = tid - 256;
            float a0 = 0.f, a1 = 0.f, a2 = 0.f, a3 = 0.f;
            #pragma unroll 8
            for (int kq = 0; kq < 32; ++kq) {
                F4H8 w; w.f4 = Wrz4f[(size_t)kq * 512 + j];
                F4H8 xx; xx.f4 = x4[kq];
                a0 = __builtin_amdgcn_fdot2(w.h2[0], xx.h2[0], a0, false);
                a1 = __builtin_amdgcn_fdot2(w.h2[1], xx.h2[1], a1, false);
                a2 = __builtin_amdgcn_fdot2(w.h2[2], xx.h2[2], a2, false);
                a3 = __builtin_amdgcn_fdot2(w.h2[3], xx.h2[3], a3, false);
            }
            redRZh[j] = (a0 + a1) + (a2 + a3);
        } else {
            int j = tid - 768;
            float a0 = 0.f, a1 = 0.f, a2 = 0.f, a3 = 0.f;
            #pragma unroll 8
            for (int kq = 0; kq < 32; ++kq) {
                F4H8 w; w.f4 = WnSf[(size_t)kq * 256 + j];   // LDS
                F4H8 xx; xx.f4 = x4[kq];
                a0 = __builtin_amdgcn_fdot2(w.h2[0], xx.h2[0], a0, false);
                a1 = __builtin_amdgcn_fdot2(w.h2[1], xx.h2[1], a1, false);
                a2 = __builtin_amdgcn_fdot2(w.h2[2], xx.h2[2], a2, false);
                a3 = __builtin_amdgcn_fdot2(w.h2[3], xx.h2[3], a3, false);
            }
            redNh[j] = (a0 + a1) + (a2 + a3);
        }
        __syncthreads();
        { // C: scores from prefetched T
            float s0 = 0.f, s1 = 0.f;
            #pragma unroll
            for (int i = 0; i < 8; ++i) {
                const F4H8& tv4 = (i==0)?treg0:(i==1)?treg1:(i==2)?treg2:(i==3)?treg3:
                                  (i==4)?treg4:(i==5)?treg5:(i==6)?treg6:treg7;
                #pragma unroll
                for (int c = 0; c < 4; ++c) {
                    int h = (hgc * 8 + i) * 4 + c;
                    float2 tv = tqv[h];
                    float vv = vls[h];
                    float T0 = (float)tv4.h2[c].x, T1 = (float)tv4.h2[c].y;
                    float d0 = fmaxf(fmaf(T0, tv.x, 1.f), 1e-6f);
                    float d1 = fmaxf(fmaf(T1, tv.x, 1.f), 1e-6f);
                    s0 = fmaf(fmaf(vv, T0, tv.y), rcp_(d0), s0);
                    s1 = fmaf(fmaf(vv, T1, tv.y), rcp_(d1), s1);
                }
            }
            redBig[hgc * 256 + 2 * l2c] = s0;
            redBig[hgc * 256 + 2 * l2c + 1] = s1;
        }
        // ---- P prefetch (first 12 quads) — overlaps phase D ----
        F4H8 pr0, pr1, pr2, pr3, pr4, pr5, pr6, pr7, pr8, pr9, pr10, pr11;
        if (tid < 768) {
            pr0.f4 = P4f[0*768+tid];  pr1.f4 = P4f[1*768+tid];
            pr2.f4 = P4f[2*768+tid];  pr3.f4 = P4f[3*768+tid];
            pr4.f4 = P4f[4*768+tid];  pr5.f4 = P4f[5*768+tid];
            pr6.f4 = P4f[6*768+tid];  pr7.f4 = P4f[7*768+tid];
            pr8.f4 = P4f[8*768+tid];  pr9.f4 = P4f[9*768+tid];
            pr10.f4 = P4f[10*768+tid]; pr11.f4 = P4f[11*768+tid];
        }
        __syncthreads();
        if (tid < 256) { // D: fused per-wave softmax (flash-style, exact)
            float sv = 0.f;
            #pragma unroll
            for (int hg = 0; hg < 8; ++hg) sv += redBig[hg * 256 + tid];
            float m = sv;
            #pragma unroll
            for (int o = 1; o < 64; o <<= 1) m = fmaxf(m, __shfl_xor(m, o, 64));
            float e = __expf(sv - m);
            attnH[tid] = __float2half(e);
            float s = e;
            #pragma unroll
            for (int o = 1; o < 64; o <<= 1) s += __shfl_xor(s, o, 64);
            if ((tid & 63) == 0) { wred[(tid >> 6) * 2] = m; wred[(tid >> 6) * 2 + 1] = s; }
        }
        __syncthreads();
        if (tid < 768) { // E': per-wave-group gate partials; 4 groups of 8 lq
            float ac0 = 0.f, ac1 = 0.f, ac2 = 0.f, ac3 = 0.f;
            F4H8 aa;
            // group 0: lq 0..7 (prefetched)
            aa.f4 = at4[0];
            ac0 = __builtin_amdgcn_fdot2(pr0.h2[0], aa.h2[0], ac0, false);
            ac0 = __builtin_amdgcn_fdot2(pr0.h2[1], aa.h2[1], ac0, false);
            ac0 = __builtin_amdgcn_fdot2(pr0.h2[2], aa.h2[2], ac0, false);
            ac0 = __builtin_amdgcn_fdot2(pr0.h2[3], aa.h2[3], ac0, false);
            aa.f4 = at4[1];
            ac0 = __builtin_amdgcn_fdot2(pr1.h2[0], aa.h2[0], ac0, false);
            ac0 = __builtin_amdgcn_fdot2(pr1.h2[1], aa.h2[1], ac0, false);
            ac0 = __builtin_amdgcn_fdot2(pr1.h2[2], aa.h2[2], ac0, false);
            ac0 = __builtin_amdgcn_fdot2(pr1.h2[3], aa.h2[3], ac0, false);
            aa.f4 = at4[2];
            ac0 = __builtin_amdgcn_fdot2(pr2.h2[0], aa.h2[0], ac0, false);
            ac0 = __builtin_amdgcn_fdot2(pr2.h2[1], aa.h2[1], ac0, false);
            ac0 = __builtin_amdgcn_fdot2(pr2.h2[2], aa.h2[2], ac0, false);
            ac0 = __builtin_amdgcn_fdot2(pr2.h2[3], aa.h2[3], ac0, false);
            aa.f4 = at4[3];
            ac0 = __builtin_amdgcn_fdot2(pr3.h2[0], aa.h2[0], ac0, false);
            ac0 = __builtin_amdgcn_fdot2(pr3.h2[1], aa.h2[1], ac0, false);
            ac0 = __builtin_amdgcn_fdot2(pr3.h2[2], aa.h2[2], ac0, false);
            ac0 = __builtin_amdgcn_fdot2(pr3.h2[3], aa.h2[3], ac0, false);
            aa.f4 = at4[4];
            ac0 = __builtin_amdgcn_fdot2(pr4.h2[0], aa.h2[0], ac0, false);
            ac0 = __builtin_amdgcn_fdot2(pr4.h2[1], aa.h2[1], ac0, false);
            ac0 = __builtin_amdgcn_fdot2(pr4.h2[2], aa.h2[2], ac0, false);
            ac0 = __builtin_amdgcn_fdot2(pr4.h2[3], aa.h2[3], ac0, false);
            aa.f4 = at4[5];
            ac0 = __builtin_amdgcn_fdot2(pr5.h2[0], aa.h2[0], ac0, false);
            ac0 = __builtin_amdgcn_fdot2(pr5.h2[1], aa.h2[1], ac0, false);
            ac0 = __builtin_amdgcn_fdot2(pr5.h2[2], aa.h2[2], ac0, false);
            ac0 = __builtin_amdgcn_fdot2(pr5.h2[3], aa.h2[3], ac0, false);
            aa.f4 = at4[6];
            ac0 = __builtin_amdgcn_fdot2(pr6.h2[0], aa.h2[0], ac0, false);
            ac0 = __builtin_amdgcn_fdot2(pr6.h2[1], aa.h2[1], ac0, false);
            ac0 = __builtin_amdgcn_fdot2(pr6.h2[2], aa.h2[2], ac0, false);
            ac0 = __builtin_amdgcn_fdot2(pr6.h2[3], aa.h2[3], ac0, false);
            aa.f4 = at4[7];
            ac0 = __builtin_amdgcn_fdot2(pr7.h2[0], aa.h2[0], ac0, false);
            ac0 = __builtin_amdgcn_fdot2(pr7.h2[1], aa.h2[1], ac0, false);
            ac0 = __builtin_amdgcn_fdot2(pr7.h2[2], aa.h2[2], ac0, false);
            ac0 = __builtin_amdgcn_fdot2(pr7.h2[3], aa.h2[3], ac0, false);
            // group 1: lq 8..11 prefetched, 12..15 loaded
            aa.f4 = at4[8];
            ac1 = __builtin_amdgcn_fdot2(pr8.h2[0], aa.h2[0], ac1, false);
            ac1 = __builtin_amdgcn_fdot2(pr8.h2[1], aa.h2[1], ac1, false);
            ac1 = __builtin_amdgcn_fdot2(pr8.h2[2], aa.h2[2], ac1, false);
            ac1 = __builtin_amdgcn_fdot2(pr8.h2[3], aa.h2[3], ac1, false);
            aa.f4 = at4[9];
            ac1 = __builtin_amdgcn_fdot2(pr9.h2[0], aa.h2[0], ac1, false);
            ac1 = __builtin_amdgcn_fdot2(pr9.h2[1], aa.h2[1], ac1, false);
            ac1 = __builtin_amdgcn_fdot2(pr9.h2[2], aa.h2[2], ac1, false);
            ac1 = __builtin_amdgcn_fdot2(pr9.h2[3], aa.h2[3], ac1, false);
            aa.f4 = at4[10];
            ac1 = __builtin_amdgcn_fdot2(pr10.h2[0], aa.h2[0], ac1, false);
            ac1 = __builtin_amdgcn_fdot2(pr10.h2[1], aa.h2[1], ac1, false);
            ac1 = __builtin_amdgcn_fdot2(pr10.h2[2], aa.h2[2], ac1, false);
            ac1 = __builtin_amdgcn_fdot2(pr10.h2[3], aa.h2[3], ac1, false);
            aa.f4 = at4[11];
            ac1 = __builtin_amdgcn_fdot2(pr11.h2[0], aa.h2[0], ac1, false);
            ac1 = __builtin_amdgcn_fdot2(pr11.h2[1], aa.h2[1], ac1, false);
            ac1 = __builtin_amdgcn_fdot2(pr11.h2[2], aa.h2[2], ac1, false);
            ac1 = __builtin_amdgcn_fdot2(pr11.h2[3], aa.h2[3], ac1, false);
            #pragma unroll
            for (int lq = 12; lq < 16; ++lq) {
                F4H8 p; p.f4 = P4f[(size_t)lq * 768 + tid];
                aa.f4 = at4[lq];
                ac1 = __builtin_amdgcn_fdot2(p.h2[0], aa.h2[0], ac1, false);
                ac1 = __builtin_amdgcn_fdot2(p.h2[1], aa.h2[1], ac1, false);
                ac1 = __builtin_amdgcn_fdot2(p.h2[2], aa.h2[2], ac1, false);
                ac1 = __builtin_amdgcn_fdot2(p.h2[3], aa.h2[3], ac1, false);
            }
            #pragma unroll
            for (int lq = 16; lq < 24; ++lq) {
                F4H8 p; p.f4 = P4f[(size_t)lq * 768 + tid];
                aa.f4 = at4[lq];
                ac2 = __builtin_amdgcn_fdot2(p.h2[0], aa.h2[0], ac2, false);
                ac2 = __builtin_amdgcn_fdot2(p.h2[1], aa.h2[1], ac2, false);
                ac2 = __builtin_amdgcn_fdot2(p.h2[2], aa.h2[2], ac2, false);
                ac2 = __builtin_amdgcn_fdot2(p.h2[3], aa.h2[3], ac2, false);
            }
            #pragma unroll
            for (int lq = 24; lq < 32; ++lq) {
                F4H8 p; p.f4 = P4f[(size_t)lq * 768 + tid];
                aa.f4 = at4[lq];
                ac3 = __builtin_amdgcn_fdot2(p.h2[0], aa.h2[0], ac3, false);
                ac3 = __builtin_amdgcn_fdot2(p.h2[1], aa.h2[1], ac3, false);
                ac3 = __builtin_amdgcn_fdot2(p.h2[2], aa.h2[2], ac3, false);
                ac3 = __builtin_amdgcn_fdot2(p.h2[3], aa.h2[3], ac3, false);
            }
            redBig[tid] = ac0;
            redBig[768 + tid] = ac1;
            redBig[1536 + tid] = ac2;
            redBig[2304 + tid] = ac3;
        }
        __syncthreads();
        if (tid < 256) { // H: combine per-wave groups + GRU update
            float m0 = wred[0], S0 = wred[1], m1 = wred[2], S1 = wred[3];
            float m2 = wred[4], S2 = wred[5], m3 = wred[6], S3 = wred[7];
            float M = fmaxf(fmaxf(m0, m1), fmaxf(m2, m3));
            float w0 = __expf(m0 - M), w1 = __expf(m1 - M);
            float w2 = __expf(m2 - M), w3 = __expf(m3 - M);
            float rs = rcp_(((w0 * S0 + w1 * S1) + (w2 * S2 + w3 * S3)));
            float gr = ((w0 * redBig[tid] + w1 * redBig[768 + tid])
                      + (w2 * redBig[1536 + tid] + w3 * redBig[2304 + tid])) * rs;
            float gz = ((w0 * redBig[256 + tid] + w1 * redBig[1024 + tid])
                      + (w2 * redBig[1792 + tid] + w3 * redBig[2560 + tid])) * rs;
            float gn = ((w0 * redBig[512 + tid] + w1 * redBig[1280 + tid])
                      + (w2 * redBig[2048 + tid] + w3 * redBig[2816 + tid])) * rs;
            float rr = redRZh[tid] + gr;
            float zz = redRZh[256 + tid] + gz;
            float nh = redNh[tid];
            float r = sigm(gir + rr + bhhS[tid]);
            float z = sigm(giz + zz + bhhS[256 + tid]);
            float n = tanh_(gin + gn + r * (nh + bhhS[512 + tid]));
            float hk = hs[tid];
            float hn = (1.f - z) * n + z * hk;
            float hnew = (len < t) ? hk : hn;        // strict '<' per reference
            hs[tid] = hnew;
            if (t < len) csum += hnew;
            float other = __shfl_xor(hnew, 1, 64);
            if ((tid & 1) == 0) {
                f16x2 v = { (_Float16)hnew, (_Float16)other };
                x2[tid >> 1] = v;
            }
        }
        __syncthreads();
    }
    if (tid < 256) outp[8192 + b * HV + tid] = csum / (float)len;
}

extern "C" void kernel_launch(void* const* d_in, const int* in_sizes, int n_in,
                              void* d_out, int out_size, void* d_ws, size_t ws_size,
                              hipStream_t stream) {
    const int* anchor_input     = (const int*)d_in[0];
    const int* anchor_length    = (const int*)d_in[1];
    const int* candidate_input  = (const int*)d_in[2];
    const int* candidate_length = (const int*)d_in[3];
    const float* emb    = (const float*)d_in[5];
    const float* W_ih_a = (const float*)d_in[6];
    const float* W_hh_a = (const float*)d_in[7];
    const float* b_ih_a = (const float*)d_in[8];
    const float* b_hh_a = (const float*)d_in[9];
    const float* W_ih_c = (const float*)d_in[10];
    const float* W_hh_c = (const float*)d_in[11];
    const float* b_ih_c = (const float*)d_in[12];
    const float* b_hh_c = (const float*)d_in[13];
    const float* Wq     = (const float*)d_in[14];
    const float* Wk     = (const float*)d_in[15];
    const float* v_att  = (const float*)d_in[16];
    float* out = (float*)d_out;

    // workspace layout (float units), ~71.3 MB
    float* ws = (float*)d_ws;
    size_t off = 0;
    float* GI_a  = ws + off; off += (size_t)LAV * BB * G3;     // 6291456 (dead after anchor)
    float* GI_c  = ws + off; off += (size_t)LCV * BB * G3;     // 6291456
    float* AO    = ws + off; off += (size_t)BB * LAV * HV;     // 2097152
    float* hid   = ws + off; off += (size_t)BB * HV;           // 8192
    float* WT_a  = ws + off; off += 300 * 768;                 // 230400
    float* WT_cx = ws + off; off += 300 * 768;                 // 230400
    __half* T4H   = (__half*)(ws + off); off += (size_t)BB * HV * LAV / 2;  // quad pack
    __half* AOH   = (__half*)(ws + off); off += (size_t)BB * LAV * HV / 2;  // [b][l][h] pairs
    __half* WhaRH = (__half*)(ws + off); off += 98304 / 2;
    __half* WhaSH = (__half*)(ws + off); off += 98304 / 2;
    __half* Wq4   = (__half*)(ws + off); off += 65536 / 2;
    __half* Wrz4  = (__half*)(ws + off); off += 131072 / 2;
    __half* Wn4   = (__half*)(ws + off); off += 65536 / 2;
    float* WcxCT  = ws + off; off += 256 * 768;                // 196608
    // P4 [1024 lq][768][4 c] half = 12.6 MB, aliased onto GI_a (dead once anchor finishes)
    __half* P4H = (__half*)GI_a;

    prep_pack<<<dim3(900, 8), 256, 0, stream>>>(W_ih_a, W_ih_c, W_hh_a, W_hh_c, Wq,
                                                WT_a, WT_cx, WhaRH, WhaSH, Wq4, Wrz4, Wn4, WcxCT);
    gemm_tile<0><<<dim3(128, 12), 256, 0, stream>>>(emb, anchor_input, DV, WT_a, DV, G3, b_ih_a, GI_a);
    gemm_tile<0><<<dim3(128, 12), 256, 0, stream>>>(emb, candidate_input, DV, WT_cx, DV, G3, b_ih_c, GI_c);
    anchor_rnn<<<32, 768, 0, stream>>>(GI_a, anchor_length, b_hh_a, WhaRH, WhaSH, AO, AOH, hid, out);
    gemm_tile<1><<<dim3(128, 4), 256, 0, stream>>>(AO, nullptr, HV, Wk, HV, HV, nullptr, (float*)T4H);
    // P = AO @ W_ih_c[:,300:]^T  -> quad pack (writes over dead GI_a)
    gemm_tile<2><<<dim3(128, 12), 256, 0, stream>>>(AO, nullptr, HV, WcxCT, HV, G3, nullptr, (float*)P4H);
    cand_rnn<<<32, 1024, 0, stream>>>(GI_c, candidate_length, b_hh_c, Wrz4, Wn4, Wq4,
                                      v_att, P4H, T4H, hid, out);
}

// Round 14
// 4692.668 us; speedup vs baseline: 1.6604x; 1.6604x over previous
//
#include <hip/hip_runtime.h>
#include <hip/hip_fp16.h>
#include <math.h>

#define BB 32
#define LAV 256
#define LCV 256
#define DV 300
#define HV 256
#define G3 768   // 3*H

typedef _Float16 f16x2 __attribute__((ext_vector_type(2)));
union F4H8 { float4 f4; f16x2 h2[4]; };
union U2H4 { uint2 u2; f16x2 h2[2]; };

// ---------- fast math helpers ----------
static __device__ __forceinline__ float rcp_(float x) { return __builtin_amdgcn_rcpf(x); }
static __device__ __forceinline__ float sigm(float x) { return rcp_(1.f + __expf(-x)); }
static __device__ __forceinline__ float tanh_(float x) { return 1.f - 2.f * rcp_(1.f + __expf(2.f * x)); }

// ---------- weight packing ----------
// c0: WT_a  [300][768] = W_ih_a^T (fp32)
// c1: WT_cx [300][768] = W_ih_c[:,:300]^T (fp32)
// c2: WhaRH half anchor reg slice [768 t][64 ii][2 e]: W_hh_a[t][2*ii+e]
// c3: WhaSH half anchor stream    [32 i2][768 j][2 s][2 e]: k2=64+2*i2+s, W_hh_a[j][2*k2+e]
// c4: Wq4   half [32 kq][256 m][4 c][2 e]  = Wq[8kq+2c+e][m]          (quad-k pack)
// c5: Wrz4  half [32 kq][512 j][4 c][2 e]  = W_hh_c[j][8kq+2c+e]      (rz hidden only)
// c6: Wn4   half [32 kq][256 j][4 c][2 e]  = W_hh_c[512+j][8kq+2c+e]  (n hidden only)
// c7: WcxCT fp32 [256 k][768 j] = W_ih_c[j][300+k]   (B operand for P gemm)
__global__ void prep_pack(const float* __restrict__ W_ih_a, const float* __restrict__ W_ih_c,
                          const float* __restrict__ W_hh_a, const float* __restrict__ W_hh_c,
                          const float* __restrict__ Wq,
                          float* __restrict__ WT_a, float* __restrict__ WT_cx,
                          __half* __restrict__ WhaRH, __half* __restrict__ WhaSH,
                          __half* __restrict__ Wq4, __half* __restrict__ Wrz4,
                          __half* __restrict__ Wn4, float* __restrict__ WcxCT)
{
    int i = blockIdx.x * 256 + threadIdx.x;
    switch (blockIdx.y) {
    case 0: if (i < 230400) { int k = i / 768, n = i % 768; WT_a[i] = W_ih_a[n * 300 + k]; } break;
    case 1: if (i < 230400) { int k = i / 768, n = i % 768; WT_cx[i] = W_ih_c[n * 556 + k]; } break;
    case 2: if (i < 98304) { int e = i & 1, r = i >> 1, ii = r & 63, j = r >> 6;
            WhaRH[i] = __float2half(W_hh_a[j * 256 + 2 * ii + e]); } break;
    case 3: if (i < 98304) { int e = i & 1, s = (i >> 1) & 1, r = i >> 2, j = r % 768, i2 = r / 768;
            int k = 2 * (64 + 2 * i2 + s) + e;
            WhaSH[i] = __float2half(W_hh_a[j * 256 + k]); } break;
    case 4: if (i < 65536) { int e = i & 1, c = (i >> 1) & 3, r = i >> 3, m = r & 255, kq = r >> 8;
            int k = 8 * kq + 2 * c + e;
            Wq4[i] = __float2half(Wq[k * 256 + m]); } break;
    case 5: if (i < 131072) { int e = i & 1, c = (i >> 1) & 3, r = i >> 3, j = r & 511, kq = r >> 9;
            int k = 8 * kq + 2 * c + e;
            Wrz4[i] = __float2half(W_hh_c[j * 256 + k]); } break;
    case 6: if (i < 65536) { int e = i & 1, c = (i >> 1) & 3, r = i >> 3, j = r & 255, kq = r >> 8;
            int k = 8 * kq + 2 * c + e;
            Wn4[i] = __float2half(W_hh_c[(512 + j) * 256 + k]); } break;
    case 7: if (i < 196608) { int k = i / 768, j = i % 768;
            WcxCT[i] = W_ih_c[j * 556 + 300 + k]; } break;
    }
}

// ---------- tiled fp32 GEMM ----------
// MODE 0: Cout[m*N+n] = acc + bias[n]                           (GI precompute)
// MODE 1: T4 half[b][hq 64][l2 128][4 c][2 e] = tanh(keys)      (h=4hq+c, l=2*l2+e)
// MODE 2: P4 half[lq 1024][768 col][4 c][2 e] = P               (l=8lq+2c+e global row)
template <int MODE>
__global__ __launch_bounds__(256) void gemm_tile(
    const float* __restrict__ X, const int* __restrict__ gidx, int ldx,
    const float* __restrict__ Wt, int K, int Nn,
    const float* __restrict__ bias, float* __restrict__ Cout)
{
    __shared__ __align__(16) float As[32][68];
    __shared__ __align__(16) float Bs[32][68];
    __shared__ int toks[64];
    int tid = threadIdx.x;
    int m0 = blockIdx.x * 64, n0 = blockIdx.y * 64;
    if (tid < 64) {
        int m = m0 + tid;
        if (gidx) { int t = m >> 5, b = m & 31; toks[tid] = gidx[b * LAV + t]; }
        else toks[tid] = m;
    }
    __syncthreads();
    float acc[4][4] = {};
    int tx = tid & 15, ty = tid >> 4;
    for (int k0 = 0; k0 < K; k0 += 32) {
        {
            int r = tid >> 2, cc = (tid & 3) * 8;
            const float* src = X + (size_t)toks[r] * ldx + k0 + cc;
            float4 v0 = {0.f,0.f,0.f,0.f}, v1 = {0.f,0.f,0.f,0.f};
            if (k0 + cc + 3 < K) v0 = *(const float4*)src;
            if (k0 + cc + 7 < K) v1 = *(const float4*)(src + 4);
            As[cc+0][r]=v0.x; As[cc+1][r]=v0.y; As[cc+2][r]=v0.z; As[cc+3][r]=v0.w;
            As[cc+4][r]=v1.x; As[cc+5][r]=v1.y; As[cc+6][r]=v1.z; As[cc+7][r]=v1.w;
        }
        {
            int kr = tid >> 4, c4 = (tid & 15) * 4;
            #pragma unroll
            for (int p = 0; p < 2; ++p) {
                float4 v = {0.f,0.f,0.f,0.f};
                int kg = k0 + kr + p * 16;
                if (kg < K) v = *(const float4*)(Wt + (size_t)kg * Nn + n0 + c4);
                *(float4*)&Bs[kr + p * 16][c4] = v;
            }
        }
        __syncthreads();
        #pragma unroll 8
        for (int kk = 0; kk < 32; ++kk) {
            float4 a4 = *(const float4*)&As[kk][ty * 4];
            float4 b4 = *(const float4*)&Bs[kk][tx * 4];
            acc[0][0]=fmaf(a4.x,b4.x,acc[0][0]); acc[0][1]=fmaf(a4.x,b4.y,acc[0][1]);
            acc[0][2]=fmaf(a4.x,b4.z,acc[0][2]); acc[0][3]=fmaf(a4.x,b4.w,acc[0][3]);
            acc[1][0]=fmaf(a4.y,b4.x,acc[1][0]); acc[1][1]=fmaf(a4.y,b4.y,acc[1][1]);
            acc[1][2]=fmaf(a4.y,b4.z,acc[1][2]); acc[1][3]=fmaf(a4.y,b4.w,acc[1][3]);
            acc[2][0]=fmaf(a4.z,b4.x,acc[2][0]); acc[2][1]=fmaf(a4.z,b4.y,acc[2][1]);
            acc[2][2]=fmaf(a4.z,b4.z,acc[2][2]); acc[2][3]=fmaf(a4.z,b4.w,acc[2][3]);
            acc[3][0]=fmaf(a4.w,b4.x,acc[3][0]); acc[3][1]=fmaf(a4.w,b4.y,acc[3][1]);
            acc[3][2]=fmaf(a4.w,b4.z,acc[3][2]); acc[3][3]=fmaf(a4.w,b4.w,acc[3][3]);
        }
        __syncthreads();
    }
    if (MODE == 0) {
        float4 bz = *(const float4*)&bias[n0 + tx * 4];
        #pragma unroll
        for (int i = 0; i < 4; ++i) {
            int m = m0 + ty * 4 + i;
            float4 o = { acc[i][0] + bz.x, acc[i][1] + bz.y, acc[i][2] + bz.z, acc[i][3] + bz.w };
            *(float4*)&Cout[(size_t)m * Nn + n0 + tx * 4] = o;
        }
    } else if (MODE == 1) {
        int b_ = m0 >> 8;
        int l0 = (m0 & 255) + ty * 4;
        f16x2* T4 = (f16x2*)Cout;
        #pragma unroll
        for (int j = 0; j < 4; ++j) {
            int h = n0 + tx * 4 + j;
            size_t base = (((size_t)(b_ * 64 + (h >> 2)) * 128) + (l0 >> 1)) * 4 + (h & 3);
            f16x2 v01 = { (_Float16)tanh_(acc[0][j]), (_Float16)tanh_(acc[1][j]) };
            f16x2 v23 = { (_Float16)tanh_(acc[2][j]), (_Float16)tanh_(acc[3][j]) };
            T4[base] = v01;
            T4[base + 4] = v23;
        }
    } else {
        int l0 = m0 + ty * 4;           // global row (b*256 + l)
        f16x2* P4 = (f16x2*)Cout;
        #pragma unroll
        for (int j = 0; j < 4; ++j) {
            int col = n0 + tx * 4 + j;
            size_t base = ((size_t)(l0 >> 3) * 768 + col) * 4 + ((l0 >> 1) & 3);
            f16x2 v01 = { (_Float16)acc[0][j], (_Float16)acc[1][j] };
            f16x2 v23 = { (_Float16)acc[2][j], (_Float16)acc[3][j] };
            P4[base] = v01;
            P4[base + 1] = v23;
        }
    }
}

// ---------- anchor GRU: one WG/batch, fp16 (reg slice + stream) — R5/R8-proven ----------
__global__ __launch_bounds__(768) void anchor_rnn(
    const float* __restrict__ GI, const int* __restrict__ lens,
    const float* __restrict__ bhh, const __half* __restrict__ WhaRH,
    const __half* __restrict__ WhaSH,
    float* __restrict__ AO, __half* __restrict__ AOH,
    float* __restrict__ hid, float* __restrict__ outp)
{
    __shared__ float gh[768];
    __shared__ __align__(16) float hs[256];
    __shared__ __align__(16) f16x2 hx2[128];
    __shared__ float bhhS[768];
    int bid = blockIdx.x, tid = threadIdx.x;
    int len = lens[bid];

    f16x2 wreg[64];
    {
        const float4* s = (const float4*)WhaRH + (size_t)tid * 16;
        #pragma unroll
        for (int u = 0; u < 16; ++u) {
            F4H8 c; c.f4 = s[u];
            wreg[4*u+0] = c.h2[0]; wreg[4*u+1] = c.h2[1];
            wreg[4*u+2] = c.h2[2]; wreg[4*u+3] = c.h2[3];
        }
    }
    if (tid < 256) hs[tid] = 0.f;
    if (tid < 128) { f16x2 z = {(_Float16)0.f, (_Float16)0.f}; hx2[tid] = z; }
    bhhS[tid] = bhh[tid];
    float sum = 0.f;
    __syncthreads();

    for (int t = 0; t < LAV; ++t) {
        { // gh[j] = W_hh_a[j,:] @ h (+ b_hh): k2 0..63 from regs + k2 64..127 streamed
            float a0=0.f,a1=0.f,a2=0.f,a3=0.f;
            const float4* xb = (const float4*)hx2;
            #pragma unroll
            for (int u = 0; u < 16; ++u) {
                F4H8 xv; xv.f4 = xb[u];
                a0 = __builtin_amdgcn_fdot2(wreg[4*u+0], xv.h2[0], a0, false);
                a1 = __builtin_amdgcn_fdot2(wreg[4*u+1], xv.h2[1], a1, false);
                a2 = __builtin_amdgcn_fdot2(wreg[4*u+2], xv.h2[2], a2, false);
                a3 = __builtin_amdgcn_fdot2(wreg[4*u+3], xv.h2[3], a3, false);
            }
            const uint2* wsp = (const uint2*)WhaSH + tid;
            float b0=0.f,b1=0.f;
            #pragma unroll
            for (int i2 = 0; i2 < 32; ++i2) {   // full 32 i2 slots (k2 64..127)
                U2H4 w; w.u2 = wsp[(size_t)i2 * 768];
                U2H4 xx; xx.u2 = *(const uint2*)&hx2[64 + 2 * i2];
                b0 = __builtin_amdgcn_fdot2(w.h2[0], xx.h2[0], b0, false);
                b1 = __builtin_amdgcn_fdot2(w.h2[1], xx.h2[1], b1, false);
            }
            gh[tid] = ((a0 + a1) + (a2 + a3)) + (b0 + b1) + bhhS[tid];
        }
        __syncthreads();
        if (tid < 256) {
            const float* gi = GI + ((size_t)t * BB + bid) * G3;
            float r = sigm(gi[tid] + gh[tid]);
            float z = sigm(gi[256 + tid] + gh[256 + tid]);
            float n = tanh_(fmaf(r, gh[512 + tid], gi[512 + tid]));
            float hk = hs[tid];
            float hn = (1.f - z) * n + z * hk;
            bool valid = (t < len);
            float hnew = valid ? hn : hk;
            hs[tid] = hnew;
            float ov = valid ? hn : 0.f;
            AO[((size_t)bid * LAV + t) * HV + tid] = ov;
            AOH[((size_t)bid * LAV + t) * HV + tid] = __float2half(ov);
            sum += ov;
            float other = __shfl_xor(hnew, 1, 64);
            if (!(tid & 1)) {
                f16x2 v = { (_Float16)hnew, (_Float16)other };
                hx2[tid >> 1] = v;
            }
        }
        __syncthreads();
    }
    if (tid < 256) {
        outp[bid * HV + tid] = sum / (float)len;
        hid[bid * HV + tid] = hs[tid];
    }
}

// ---------- candidate GRU + attention: one WG/batch ----------
// R12 structure + Wn in LDS + fused per-wave flash softmax (5 barriers).
// NO registers held across barriers beyond scalars (1024-thr VGPR cap = 64).
__global__ __launch_bounds__(1024) void cand_rnn(
    const float* __restrict__ GI, const int* __restrict__ lens,
    const float* __restrict__ bhh, const __half* __restrict__ Wrz4,
    const __half* __restrict__ Wn4, const __half* __restrict__ Wq4,
    const float* __restrict__ v_att, const __half* __restrict__ P4H,
    const __half* __restrict__ T4H, const float* __restrict__ hid,
    float* __restrict__ outp)
{
    __shared__ __align__(16) __half WnS[65536];    // 128 KB, staged once
    __shared__ __align__(16) f16x2 x2[128];        // h pairs (read as float4 quads)
    __shared__ __align__(16) float hs[256];
    __shared__ __align__(16) float2 tqv[256];      // {tq, v*tq}
    __shared__ float vls[256];
    __shared__ __align__(16) __half attnH[256];    // per-wave exp(s-m_w), fp16
    __shared__ __align__(16) float redBig[3072];   // scores (C) -> gateC groups (E')
    __shared__ __align__(16) float redRZh[512];
    __shared__ __align__(16) float redNh[256];
    __shared__ float bhhS[768];
    __shared__ float wred[8];                      // {m_w, S_w} x 4 waves

    int tid = threadIdx.x;
    int b = blockIdx.x;
    int len = lens[b];

    const float4* Wq4f  = (const float4*)Wq4;
    const float4* Wrz4f = (const float4*)Wrz4;
    const float4* T4f   = (const float4*)T4H + (size_t)b * 64 * 128;
    const float4* P4f   = (const float4*)P4H + (size_t)b * 32 * 768;
    const float4* x4    = (const float4*)x2;
    const float4* at4   = (const float4*)attnH;
    const float4* WnSf  = (const float4*)WnS;

    { // stage Wn into LDS once (8192 float4)
        const float4* s = (const float4*)Wn4;
        float4* d = (float4*)WnS;
        #pragma unroll
        for (int u = 0; u < 8; ++u) d[u * 1024 + tid] = s[u * 1024 + tid];
    }
    if (tid < 256) { hs[tid] = hid[b * HV + tid]; vls[tid] = v_att[tid]; }
    if (tid < 768) bhhS[tid] = bhh[tid];
    __syncthreads();
    if (tid < 128) {
        f16x2 v = { (_Float16)hs[2 * tid], (_Float16)hs[2 * tid + 1] };
        x2[tid] = v;
    }
    __syncthreads();

    float csum = 0.f;

    for (int t = 0; t < LCV; ++t) {
        float gir = 0.f, giz = 0.f, gin = 0.f;
        // ---- A: full-output role split ----
        if (tid < 256) {
            const float* gi = GI + ((size_t)t * BB + b) * G3 + tid;
            gir = gi[0]; giz = gi[256]; gin = gi[512];
            int m = tid;
            float a0 = 0.f, a1 = 0.f, a2 = 0.f, a3 = 0.f;
            #pragma unroll 8
            for (int kq = 0; kq < 32; ++kq) {
                F4H8 w; w.f4 = Wq4f[(size_t)kq * 256 + m];
                F4H8 xx; xx.f4 = x4[kq];
                a0 = __builtin_amdgcn_fdot2(w.h2[0], xx.h2[0], a0, false);
                a1 = __builtin_amdgcn_fdot2(w.h2[1], xx.h2[1], a1, false);
                a2 = __builtin_amdgcn_fdot2(w.h2[2], xx.h2[2], a2, false);
                a3 = __builtin_amdgcn_fdot2(w.h2[3], xx.h2[3], a3, false);
            }
            float tq = tanh_((a0 + a1) + (a2 + a3));
            tqv[m] = make_float2(tq, vls[m] * tq);
        } else if (tid < 768) {
            int j = tid - 256;
            float a0 = 0.f, a1 = 0.f, a2 = 0.f, a3 = 0.f;
            #pragma unroll 8
            for (int kq = 0; kq < 32; ++kq) {
                F4H8 w; w.f4 = Wrz4f[(size_t)kq * 512 + j];
                F4H8 xx; xx.f4 = x4[kq];
                a0 = __builtin_amdgcn_fdot2(w.h2[0], xx.h2[0], a0, false);
                a1 = __builtin_amdgcn_fdot2(w.h2[1], xx.h2[1], a1, false);
                a2 = __builtin_amdgcn_fdot2(w.h2[2], xx.h2[2], a2, false);
                a3 = __builtin_amdgcn_fdot2(w.h2[3], xx.h2[3], a3, false);
            }
            redRZh[j] = (a0 + a1) + (a2 + a3);
        } else {
            int j = tid - 768;
            float a0 = 0.f, a1 = 0.f, a2 = 0.f, a3 = 0.f;
            #pragma unroll 8
            for (int kq = 0; kq < 32; ++kq) {
                F4H8 w; w.f4 = WnSf[(size_t)kq * 256 + j];   // LDS (step-invariant)
                F4H8 xx; xx.f4 = x4[kq];
                a0 = __builtin_amdgcn_fdot2(w.h2[0], xx.h2[0], a0, false);
                a1 = __builtin_amdgcn_fdot2(w.h2[1], xx.h2[1], a1, false);
                a2 = __builtin_amdgcn_fdot2(w.h2[2], xx.h2[2], a2, false);
                a3 = __builtin_amdgcn_fdot2(w.h2[3], xx.h2[3], a3, false);
            }
            redNh[j] = (a0 + a1) + (a2 + a3);
        }
        __syncthreads();
        { // C: scores; 8 float4 loads, 32 h per thread
            int l2 = tid & 127, hg = tid >> 7;
            const float4* Tb = T4f + (size_t)(hg * 8) * 128 + l2;
            float s0 = 0.f, s1 = 0.f;
            #pragma unroll
            for (int i = 0; i < 8; ++i) {
                F4H8 tv4; tv4.f4 = Tb[(size_t)i * 128];
                #pragma unroll
                for (int c = 0; c < 4; ++c) {
                    int h = (hg * 8 + i) * 4 + c;
                    float2 tv = tqv[h];
                    float vv = vls[h];
                    float T0 = (float)tv4.h2[c].x, T1 = (float)tv4.h2[c].y;
                    float d0 = fmaxf(fmaf(T0, tv.x, 1.f), 1e-6f);
                    float d1 = fmaxf(fmaf(T1, tv.x, 1.f), 1e-6f);
                    s0 = fmaf(fmaf(vv, T0, tv.y), rcp_(d0), s0);
                    s1 = fmaf(fmaf(vv, T1, tv.y), rcp_(d1), s1);
                }
            }
            redBig[hg * 256 + 2 * l2] = s0;
            redBig[hg * 256 + 2 * l2 + 1] = s1;
        }
        __syncthreads();
        if (tid < 256) { // D: fused per-wave softmax (flash-style, exact combine in H)
            float sv = 0.f;
            #pragma unroll
            for (int hg = 0; hg < 8; ++hg) sv += redBig[hg * 256 + tid];
            float m = sv;
            #pragma unroll
            for (int o = 1; o < 64; o <<= 1) m = fmaxf(m, __shfl_xor(m, o, 64));
            float e = __expf(sv - m);
            attnH[tid] = __float2half(e);
            float s = e;
            #pragma unroll
            for (int o = 1; o < 64; o <<= 1) s += __shfl_xor(s, o, 64);
            if ((tid & 63) == 0) { wred[(tid >> 6) * 2] = m; wred[(tid >> 6) * 2 + 1] = s; }
        }
        __syncthreads();
        if (tid < 768) { // E': per-wave-group gate partials; 32 direct float4 loads
            float ac0 = 0.f, ac1 = 0.f, ac2 = 0.f, ac3 = 0.f;
            #pragma unroll
            for (int lq = 0; lq < 8; ++lq) {
                F4H8 p; p.f4 = P4f[(size_t)lq * 768 + tid];
                F4H8 aa; aa.f4 = at4[lq];
                ac0 = __builtin_amdgcn_fdot2(p.h2[0], aa.h2[0], ac0, false);
                ac0 = __builtin_amdgcn_fdot2(p.h2[1], aa.h2[1], ac0, false);
                ac0 = __builtin_amdgcn_fdot2(p.h2[2], aa.h2[2], ac0, false);
                ac0 = __builtin_amdgcn_fdot2(p.h2[3], aa.h2[3], ac0, false);
            }
            #pragma unroll
            for (int lq = 8; lq < 16; ++lq) {
                F4H8 p; p.f4 = P4f[(size_t)lq * 768 + tid];
                F4H8 aa; aa.f4 = at4[lq];
                ac1 = __builtin_amdgcn_fdot2(p.h2[0], aa.h2[0], ac1, false);
                ac1 = __builtin_amdgcn_fdot2(p.h2[1], aa.h2[1], ac1, false);
                ac1 = __builtin_amdgcn_fdot2(p.h2[2], aa.h2[2], ac1, false);
                ac1 = __builtin_amdgcn_fdot2(p.h2[3], aa.h2[3], ac1, false);
            }
            #pragma unroll
            for (int lq = 16; lq < 24; ++lq) {
                F4H8 p; p.f4 = P4f[(size_t)lq * 768 + tid];
                F4H8 aa; aa.f4 = at4[lq];
                ac2 = __builtin_amdgcn_fdot2(p.h2[0], aa.h2[0], ac2, false);
                ac2 = __builtin_amdgcn_fdot2(p.h2[1], aa.h2[1], ac2, false);
                ac2 = __builtin_amdgcn_fdot2(p.h2[2], aa.h2[2], ac2, false);
                ac2 = __builtin_amdgcn_fdot2(p.h2[3], aa.h2[3], ac2, false);
            }
            #pragma unroll
            for (int lq = 24; lq < 32; ++lq) {
                F4H8 p; p.f4 = P4f[(size_t)lq * 768 + tid];
                F4H8 aa; aa.f4 = at4[lq];
                ac3 = __builtin_amdgcn_fdot2(p.h2[0], aa.h2[0], ac3, false);
                ac3 = __builtin_amdgcn_fdot2(p.h2[1], aa.h2[1], ac3, false);
                ac3 = __builtin_amdgcn_fdot2(p.h2[2], aa.h2[2], ac3, false);
                ac3 = __builtin_amdgcn_fdot2(p.h2[3], aa.h2[3], ac3, false);
            }
            redBig[tid] = ac0;
            redBig[768 + tid] = ac1;
            redBig[1536 + tid] = ac2;
            redBig[2304 + tid] = ac3;
        }
        __syncthreads();
        if (tid < 256) { // H: flash combine + GRU update
            float m0 = wred[0], S0 = wred[1], m1 = wred[2], S1 = wred[3];
            float m2 = wred[4], S2 = wred[5], m3 = wred[6], S3 = wred[7];
            float M = fmaxf(fmaxf(m0, m1), fmaxf(m2, m3));
            float w0 = __expf(m0 - M), w1 = __expf(m1 - M);
            float w2 = __expf(m2 - M), w3 = __expf(m3 - M);
            float rs = rcp_((w0 * S0 + w1 * S1) + (w2 * S2 + w3 * S3));
            float gr = ((w0 * redBig[tid] + w1 * redBig[768 + tid])
                      + (w2 * redBig[1536 + tid] + w3 * redBig[2304 + tid])) * rs;
            float gz = ((w0 * redBig[256 + tid] + w1 * redBig[1024 + tid])
                      + (w2 * redBig[1792 + tid] + w3 * redBig[2560 + tid])) * rs;
            float gn = ((w0 * redBig[512 + tid] + w1 * redBig[1280 + tid])
                      + (w2 * redBig[2048 + tid] + w3 * redBig[2816 + tid])) * rs;
            float rr = redRZh[tid] + gr;
            float zz = redRZh[256 + tid] + gz;
            float nh = redNh[tid];
            float r = sigm(gir + rr + bhhS[tid]);
            float z = sigm(giz + zz + bhhS[256 + tid]);
            float n = tanh_(gin + gn + r * (nh + bhhS[512 + tid]));
            float hk = hs[tid];
            float hn = (1.f - z) * n + z * hk;
            float hnew = (len < t) ? hk : hn;        // strict '<' per reference
            hs[tid] = hnew;
            if (t < len) csum += hnew;
            float other = __shfl_xor(hnew, 1, 64);
            if ((tid & 1) == 0) {
                f16x2 v = { (_Float16)hnew, (_Float16)other };
                x2[tid >> 1] = v;
            }
        }
        __syncthreads();
    }
    if (tid < 256) outp[8192 + b * HV + tid] = csum / (float)len;
}

extern "C" void kernel_launch(void* const* d_in, const int* in_sizes, int n_in,
                              void* d_out, int out_size, void* d_ws, size_t ws_size,
                              hipStream_t stream) {
    const int* anchor_input     = (const int*)d_in[0];
    const int* anchor_length    = (const int*)d_in[1];
    const int* candidate_input  = (const int*)d_in[2];
    const int* candidate_length = (const int*)d_in[3];
    const float* emb    = (const float*)d_in[5];
    const float* W_ih_a = (const float*)d_in[6];
    const float* W_hh_a = (const float*)d_in[7];
    const float* b_ih_a = (const float*)d_in[8];
    const float* b_hh_a = (const float*)d_in[9];
    const float* W_ih_c = (const float*)d_in[10];
    const float* W_hh_c = (const float*)d_in[11];
    const float* b_ih_c = (const float*)d_in[12];
    const float* b_hh_c = (const float*)d_in[13];
    const float* Wq     = (const float*)d_in[14];
    const float* Wk     = (const float*)d_in[15];
    const float* v_att  = (const float*)d_in[16];
    float* out = (float*)d_out;

    // workspace layout (float units), ~71.3 MB
    float* ws = (float*)d_ws;
    size_t off = 0;
    float* GI_a  = ws + off; off += (size_t)LAV * BB * G3;     // 6291456 (dead after anchor)
    float* GI_c  = ws + off; off += (size_t)LCV * BB * G3;     // 6291456
    float* AO    = ws + off; off += (size_t)BB * LAV * HV;     // 2097152
    float* hid   = ws + off; off += (size_t)BB * HV;           // 8192
    float* WT_a  = ws + off; off += 300 * 768;                 // 230400
    float* WT_cx = ws + off; off += 300 * 768;                 // 230400
    __half* T4H   = (__half*)(ws + off); off += (size_t)BB * HV * LAV / 2;  // quad pack
    __half* AOH   = (__half*)(ws + off); off += (size_t)BB * LAV * HV / 2;  // [b][l][h] pairs
    __half* WhaRH = (__half*)(ws + off); off += 98304 / 2;
    __half* WhaSH = (__half*)(ws + off); off += 98304 / 2;
    __half* Wq4   = (__half*)(ws + off); off += 65536 / 2;
    __half* Wrz4  = (__half*)(ws + off); off += 131072 / 2;
    __half* Wn4   = (__half*)(ws + off); off += 65536 / 2;
    float* WcxCT  = ws + off; off += 256 * 768;                // 196608
    // P4 [1024 lq][768][4 c] half = 12.6 MB, aliased onto GI_a (dead once anchor finishes)
    __half* P4H = (__half*)GI_a;

    prep_pack<<<dim3(900, 8), 256, 0, stream>>>(W_ih_a, W_ih_c, W_hh_a, W_hh_c, Wq,
                                                WT_a, WT_cx, WhaRH, WhaSH, Wq4, Wrz4, Wn4, WcxCT);
    gemm_tile<0><<<dim3(128, 12), 256, 0, stream>>>(emb, anchor_input, DV, WT_a, DV, G3, b_ih_a, GI_a);
    gemm_tile<0><<<dim3(128, 12), 256, 0, stream>>>(emb, candidate_input, DV, WT_cx, DV, G3, b_ih_c, GI_c);
    anchor_rnn<<<32, 768, 0, stream>>>(GI_a, anchor_length, b_hh_a, WhaRH, WhaSH, AO, AOH, hid, out);
    gemm_tile<1><<<dim3(128, 4), 256, 0, stream>>>(AO, nullptr, HV, Wk, HV, HV, nullptr, (float*)T4H);
    // P = AO @ W_ih_c[:,300:]^T  -> quad pack (writes over dead GI_a)
    gemm_tile<2><<<dim3(128, 12), 256, 0, stream>>>(AO, nullptr, HV, WcxCT, HV, G3, nullptr, (float*)P4H);
    cand_rnn<<<32, 1024, 0, stream>>>(GI_c, candidate_length, b_hh_c, Wrz4, Wn4, Wq4,
                                      v_att, P4H, T4H, hid, out);
}

// Round 15
// 3552.767 us; speedup vs baseline: 2.1931x; 1.3208x over previous
//
#include <hip/hip_runtime.h>
#include <hip/hip_fp16.h>
#include <math.h>

#define BB 32
#define LAV 256
#define LCV 256
#define DV 300
#define HV 256
#define G3 768   // 3*H

typedef _Float16 f16x2 __attribute__((ext_vector_type(2)));
union F4H8 { float4 f4; f16x2 h2[4]; };
union U2H4 { uint2 u2; f16x2 h2[2]; };

// ---------- fast math helpers ----------
static __device__ __forceinline__ float rcp_(float x) { return __builtin_amdgcn_rcpf(x); }
static __device__ __forceinline__ float sigm(float x) { return rcp_(1.f + __expf(-x)); }
static __device__ __forceinline__ float tanh_(float x) { return 1.f - 2.f * rcp_(1.f + __expf(2.f * x)); }

// ---------- weight packing ----------
// c0: WT_a  [300][768] = W_ih_a^T (fp32)
// c1: WT_cx [300][768] = W_ih_c[:,:300]^T (fp32)
// c2: WhaRH half anchor reg slice [768 t][64 ii][2 e]: W_hh_a[t][2*ii+e]
// c3: WhaSH half anchor stream    [32 i2][768 j][2 s][2 e]: k2=64+2*i2+s, W_hh_a[j][2*k2+e]
// c4: Wq4   half [32 kq][256 m][4 c][2 e]  = Wq[8kq+2c+e][m]          (quad-k pack)
// c5: Wrz4  half [32 kq][512 j][4 c][2 e]  = W_hh_c[j][8kq+2c+e]      (rz hidden only)
// c6: Wn4   half [32 kq][256 j][4 c][2 e]  = W_hh_c[512+j][8kq+2c+e]  (n hidden only)
// c7: WcxCT fp32 [256 k][768 j] = W_ih_c[j][300+k]   (B operand for P gemm)
__global__ void prep_pack(const float* __restrict__ W_ih_a, const float* __restrict__ W_ih_c,
                          const float* __restrict__ W_hh_a, const float* __restrict__ W_hh_c,
                          const float* __restrict__ Wq,
                          float* __restrict__ WT_a, float* __restrict__ WT_cx,
                          __half* __restrict__ WhaRH, __half* __restrict__ WhaSH,
                          __half* __restrict__ Wq4, __half* __restrict__ Wrz4,
                          __half* __restrict__ Wn4, float* __restrict__ WcxCT)
{
    int i = blockIdx.x * 256 + threadIdx.x;
    switch (blockIdx.y) {
    case 0: if (i < 230400) { int k = i / 768, n = i % 768; WT_a[i] = W_ih_a[n * 300 + k]; } break;
    case 1: if (i < 230400) { int k = i / 768, n = i % 768; WT_cx[i] = W_ih_c[n * 556 + k]; } break;
    case 2: if (i < 98304) { int e = i & 1, r = i >> 1, ii = r & 63, j = r >> 6;
            WhaRH[i] = __float2half(W_hh_a[j * 256 + 2 * ii + e]); } break;
    case 3: if (i < 98304) { int e = i & 1, s = (i >> 1) & 1, r = i >> 2, j = r % 768, i2 = r / 768;
            int k = 2 * (64 + 2 * i2 + s) + e;
            WhaSH[i] = __float2half(W_hh_a[j * 256 + k]); } break;
    case 4: if (i < 65536) { int e = i & 1, c = (i >> 1) & 3, r = i >> 3, m = r & 255, kq = r >> 8;
            int k = 8 * kq + 2 * c + e;
            Wq4[i] = __float2half(Wq[k * 256 + m]); } break;
    case 5: if (i < 131072) { int e = i & 1, c = (i >> 1) & 3, r = i >> 3, j = r & 511, kq = r >> 9;
            int k = 8 * kq + 2 * c + e;
            Wrz4[i] = __float2half(W_hh_c[j * 256 + k]); } break;
    case 6: if (i < 65536) { int e = i & 1, c = (i >> 1) & 3, r = i >> 3, j = r & 255, kq = r >> 8;
            int k = 8 * kq + 2 * c + e;
            Wn4[i] = __float2half(W_hh_c[(512 + j) * 256 + k]); } break;
    case 7: if (i < 196608) { int k = i / 768, j = i % 768;
            WcxCT[i] = W_ih_c[j * 556 + 300 + k]; } break;
    }
}

// ---------- tiled fp32 GEMM ----------
// MODE 0: Cout[m*N+n] = acc + bias[n]                           (GI precompute)
// MODE 1: T4 half[b][hq 64][l2 128][4 c][2 e] = tanh(keys)      (h=4hq+c, l=2*l2+e)
// MODE 2: P4 half[lq 1024][768 col][4 c][2 e] = P               (l=8lq+2c+e global row)
template <int MODE>
__global__ __launch_bounds__(256) void gemm_tile(
    const float* __restrict__ X, const int* __restrict__ gidx, int ldx,
    const float* __restrict__ Wt, int K, int Nn,
    const float* __restrict__ bias, float* __restrict__ Cout)
{
    __shared__ __align__(16) float As[32][68];
    __shared__ __align__(16) float Bs[32][68];
    __shared__ int toks[64];
    int tid = threadIdx.x;
    int m0 = blockIdx.x * 64, n0 = blockIdx.y * 64;
    if (tid < 64) {
        int m = m0 + tid;
        if (gidx) { int t = m >> 5, b = m & 31; toks[tid] = gidx[b * LAV + t]; }
        else toks[tid] = m;
    }
    __syncthreads();
    float acc[4][4] = {};
    int tx = tid & 15, ty = tid >> 4;
    for (int k0 = 0; k0 < K; k0 += 32) {
        {
            int r = tid >> 2, cc = (tid & 3) * 8;
            const float* src = X + (size_t)toks[r] * ldx + k0 + cc;
            float4 v0 = {0.f,0.f,0.f,0.f}, v1 = {0.f,0.f,0.f,0.f};
            if (k0 + cc + 3 < K) v0 = *(const float4*)src;
            if (k0 + cc + 7 < K) v1 = *(const float4*)(src + 4);
            As[cc+0][r]=v0.x; As[cc+1][r]=v0.y; As[cc+2][r]=v0.z; As[cc+3][r]=v0.w;
            As[cc+4][r]=v1.x; As[cc+5][r]=v1.y; As[cc+6][r]=v1.z; As[cc+7][r]=v1.w;
        }
        {
            int kr = tid >> 4, c4 = (tid & 15) * 4;
            #pragma unroll
            for (int p = 0; p < 2; ++p) {
                float4 v = {0.f,0.f,0.f,0.f};
                int kg = k0 + kr + p * 16;
                if (kg < K) v = *(const float4*)(Wt + (size_t)kg * Nn + n0 + c4);
                *(float4*)&Bs[kr + p * 16][c4] = v;
            }
        }
        __syncthreads();
        #pragma unroll 8
        for (int kk = 0; kk < 32; ++kk) {
            float4 a4 = *(const float4*)&As[kk][ty * 4];
            float4 b4 = *(const float4*)&Bs[kk][tx * 4];
            acc[0][0]=fmaf(a4.x,b4.x,acc[0][0]); acc[0][1]=fmaf(a4.x,b4.y,acc[0][1]);
            acc[0][2]=fmaf(a4.x,b4.z,acc[0][2]); acc[0][3]=fmaf(a4.x,b4.w,acc[0][3]);
            acc[1][0]=fmaf(a4.y,b4.x,acc[1][0]); acc[1][1]=fmaf(a4.y,b4.y,acc[1][1]);
            acc[1][2]=fmaf(a4.y,b4.z,acc[1][2]); acc[1][3]=fmaf(a4.y,b4.w,acc[1][3]);
            acc[2][0]=fmaf(a4.z,b4.x,acc[2][0]); acc[2][1]=fmaf(a4.z,b4.y,acc[2][1]);
            acc[2][2]=fmaf(a4.z,b4.z,acc[2][2]); acc[2][3]=fmaf(a4.z,b4.w,acc[2][3]);
            acc[3][0]=fmaf(a4.w,b4.x,acc[3][0]); acc[3][1]=fmaf(a4.w,b4.y,acc[3][1]);
            acc[3][2]=fmaf(a4.w,b4.z,acc[3][2]); acc[3][3]=fmaf(a4.w,b4.w,acc[3][3]);
        }
        __syncthreads();
    }
    if (MODE == 0) {
        float4 bz = *(const float4*)&bias[n0 + tx * 4];
        #pragma unroll
        for (int i = 0; i < 4; ++i) {
            int m = m0 + ty * 4 + i;
            float4 o = { acc[i][0] + bz.x, acc[i][1] + bz.y, acc[i][2] + bz.z, acc[i][3] + bz.w };
            *(float4*)&Cout[(size_t)m * Nn + n0 + tx * 4] = o;
        }
    } else if (MODE == 1) {
        int b_ = m0 >> 8;
        int l0 = (m0 & 255) + ty * 4;
        f16x2* T4 = (f16x2*)Cout;
        #pragma unroll
        for (int j = 0; j < 4; ++j) {
            int h = n0 + tx * 4 + j;
            size_t base = (((size_t)(b_ * 64 + (h >> 2)) * 128) + (l0 >> 1)) * 4 + (h & 3);
            f16x2 v01 = { (_Float16)tanh_(acc[0][j]), (_Float16)tanh_(acc[1][j]) };
            f16x2 v23 = { (_Float16)tanh_(acc[2][j]), (_Float16)tanh_(acc[3][j]) };
            T4[base] = v01;
            T4[base + 4] = v23;
        }
    } else {
        int l0 = m0 + ty * 4;           // global row (b*256 + l)
        f16x2* P4 = (f16x2*)Cout;
        #pragma unroll
        for (int j = 0; j < 4; ++j) {
            int col = n0 + tx * 4 + j;
            size_t base = ((size_t)(l0 >> 3) * 768 + col) * 4 + ((l0 >> 1) & 3);
            f16x2 v01 = { (_Float16)acc[0][j], (_Float16)acc[1][j] };
            f16x2 v23 = { (_Float16)acc[2][j], (_Float16)acc[3][j] };
            P4[base] = v01;
            P4[base + 1] = v23;
        }
    }
}

// ---------- anchor GRU: one WG/batch, fp16 (reg slice + stream) — R5/R8-proven ----------
__global__ __launch_bounds__(768) void anchor_rnn(
    const float* __restrict__ GI, const int* __restrict__ lens,
    const float* __restrict__ bhh, const __half* __restrict__ WhaRH,
    const __half* __restrict__ WhaSH,
    float* __restrict__ AO, __half* __restrict__ AOH,
    float* __restrict__ hid, float* __restrict__ outp)
{
    __shared__ float gh[768];
    __shared__ __align__(16) float hs[256];
    __shared__ __align__(16) f16x2 hx2[128];
    __shared__ float bhhS[768];
    int bid = blockIdx.x, tid = threadIdx.x;
    int len = lens[bid];

    f16x2 wreg[64];
    {
        const float4* s = (const float4*)WhaRH + (size_t)tid * 16;
        #pragma unroll
        for (int u = 0; u < 16; ++u) {
            F4H8 c; c.f4 = s[u];
            wreg[4*u+0] = c.h2[0]; wreg[4*u+1] = c.h2[1];
            wreg[4*u+2] = c.h2[2]; wreg[4*u+3] = c.h2[3];
        }
    }
    if (tid < 256) hs[tid] = 0.f;
    if (tid < 128) { f16x2 z = {(_Float16)0.f, (_Float16)0.f}; hx2[tid] = z; }
    bhhS[tid] = bhh[tid];
    float sum = 0.f;
    __syncthreads();

    for (int t = 0; t < LAV; ++t) {
        { // gh[j] = W_hh_a[j,:] @ h (+ b_hh): k2 0..63 from regs + k2 64..127 streamed
            float a0=0.f,a1=0.f,a2=0.f,a3=0.f;
            const float4* xb = (const float4*)hx2;
            #pragma unroll
            for (int u = 0; u < 16; ++u) {
                F4H8 xv; xv.f4 = xb[u];
                a0 = __builtin_amdgcn_fdot2(wreg[4*u+0], xv.h2[0], a0, false);
                a1 = __builtin_amdgcn_fdot2(wreg[4*u+1], xv.h2[1], a1, false);
                a2 = __builtin_amdgcn_fdot2(wreg[4*u+2], xv.h2[2], a2, false);
                a3 = __builtin_amdgcn_fdot2(wreg[4*u+3], xv.h2[3], a3, false);
            }
            const uint2* wsp = (const uint2*)WhaSH + tid;
            float b0=0.f,b1=0.f;
            #pragma unroll
            for (int i2 = 0; i2 < 32; ++i2) {   // full 32 i2 slots (k2 64..127)
                U2H4 w; w.u2 = wsp[(size_t)i2 * 768];
                U2H4 xx; xx.u2 = *(const uint2*)&hx2[64 + 2 * i2];
                b0 = __builtin_amdgcn_fdot2(w.h2[0], xx.h2[0], b0, false);
                b1 = __builtin_amdgcn_fdot2(w.h2[1], xx.h2[1], b1, false);
            }
            gh[tid] = ((a0 + a1) + (a2 + a3)) + (b0 + b1) + bhhS[tid];
        }
        __syncthreads();
        if (tid < 256) {
            const float* gi = GI + ((size_t)t * BB + bid) * G3;
            float r = sigm(gi[tid] + gh[tid]);
            float z = sigm(gi[256 + tid] + gh[256 + tid]);
            float n = tanh_(fmaf(r, gh[512 + tid], gi[512 + tid]));
            float hk = hs[tid];
            float hn = (1.f - z) * n + z * hk;
            bool valid = (t < len);
            float hnew = valid ? hn : hk;
            hs[tid] = hnew;
            float ov = valid ? hn : 0.f;
            AO[((size_t)bid * LAV + t) * HV + tid] = ov;
            AOH[((size_t)bid * LAV + t) * HV + tid] = __float2half(ov);
            sum += ov;
            float other = __shfl_xor(hnew, 1, 64);
            if (!(tid & 1)) {
                f16x2 v = { (_Float16)hnew, (_Float16)other };
                hx2[tid >> 1] = v;
            }
        }
        __syncthreads();
    }
    if (tid < 256) {
        outp[bid * HV + tid] = sum / (float)len;
        hid[bid * HV + tid] = hs[tid];
    }
}

// ---------- candidate GRU + attention: one WG/batch; quad-k float4 loads throughout ----------
// A(q full+tanh | rzh full | nh full; GI prefetch) C(scores) D1(max) D2(exp+sum)
// E'(gateC = attn @ P) H(gate + h update)
__global__ __launch_bounds__(1024) void cand_rnn(
    const float* __restrict__ GI, const int* __restrict__ lens,
    const float* __restrict__ bhh, const __half* __restrict__ Wrz4,
    const __half* __restrict__ Wn4, const __half* __restrict__ Wq4,
    const float* __restrict__ v_att, const __half* __restrict__ P4H,
    const __half* __restrict__ T4H, const float* __restrict__ hid,
    float* __restrict__ outp)
{
    __shared__ __align__(16) f16x2 x2[128];        // h pairs (read as float4 quads)
    __shared__ __align__(16) float hs[256];
    __shared__ __align__(16) float2 tqv[256];      // {tq, v*tq}
    __shared__ float vls[256];
    __shared__ __align__(16) __half attnH[256];    // exp(s-mx) fp16 (read as float4 quads)
    __shared__ __align__(16) float redBig[2048];   // score partials (C)
    __shared__ __align__(16) float redRZh[512];    // A -> H (complete sums)
    __shared__ __align__(16) float redNh[256];     // A -> H (complete sums)
    __shared__ __align__(16) float gateC[768];     // E' -> H
    __shared__ float bhhS[768];
    __shared__ float wred[8];

    int tid = threadIdx.x;
    int b = blockIdx.x;
    int len = lens[b];

    const float4* Wq4f  = (const float4*)Wq4;
    const float4* Wrz4f = (const float4*)Wrz4;
    const float4* Wn4f  = (const float4*)Wn4;
    const float4* T4f   = (const float4*)T4H + (size_t)b * 64 * 128;
    const float4* P4f   = (const float4*)P4H + (size_t)b * 32 * 768;
    const float4* x4    = (const float4*)x2;
    const float4* at4   = (const float4*)attnH;

    if (tid < 256) { hs[tid] = hid[b * HV + tid]; vls[tid] = v_att[tid]; }
    if (tid < 768) bhhS[tid] = bhh[tid];
    __syncthreads();
    if (tid < 128) {
        f16x2 v = { (_Float16)hs[2 * tid], (_Float16)hs[2 * tid + 1] };
        x2[tid] = v;
    }
    __syncthreads();

    float csum = 0.f;

    for (int t = 0; t < LCV; ++t) {
        float gir = 0.f, giz = 0.f, gin = 0.f;
        // ---- A: full-output role split; 32 float4 loads + 128 fdot2 per thread ----
        if (tid < 256) {
            const float* gi = GI + ((size_t)t * BB + b) * G3 + tid;
            gir = gi[0]; giz = gi[256]; gin = gi[512];
            int m = tid;
            float a0 = 0.f, a1 = 0.f, a2 = 0.f, a3 = 0.f;
            #pragma unroll 8
            for (int kq = 0; kq < 32; ++kq) {
                F4H8 w; w.f4 = Wq4f[(size_t)kq * 256 + m];
                F4H8 xx; xx.f4 = x4[kq];
                a0 = __builtin_amdgcn_fdot2(w.h2[0], xx.h2[0], a0, false);
                a1 = __builtin_amdgcn_fdot2(w.h2[1], xx.h2[1], a1, false);
                a2 = __builtin_amdgcn_fdot2(w.h2[2], xx.h2[2], a2, false);
                a3 = __builtin_amdgcn_fdot2(w.h2[3], xx.h2[3], a3, false);
            }
            float tq = tanh_((a0 + a1) + (a2 + a3));
            tqv[m] = make_float2(tq, vls[m] * tq);
        } else if (tid < 768) {
            int j = tid - 256;
            float a0 = 0.f, a1 = 0.f, a2 = 0.f, a3 = 0.f;
            #pragma unroll 8
            for (int kq = 0; kq < 32; ++kq) {
                F4H8 w; w.f4 = Wrz4f[(size_t)kq * 512 + j];
                F4H8 xx; xx.f4 = x4[kq];
                a0 = __builtin_amdgcn_fdot2(w.h2[0], xx.h2[0], a0, false);
                a1 = __builtin_amdgcn_fdot2(w.h2[1], xx.h2[1], a1, false);
                a2 = __builtin_amdgcn_fdot2(w.h2[2], xx.h2[2], a2, false);
                a3 = __builtin_amdgcn_fdot2(w.h2[3], xx.h2[3], a3, false);
            }
            redRZh[j] = (a0 + a1) + (a2 + a3);
        } else {
            int j = tid - 768;
            float a0 = 0.f, a1 = 0.f, a2 = 0.f, a3 = 0.f;
            #pragma unroll 8
            for (int kq = 0; kq < 32; ++kq) {
                F4H8 w; w.f4 = Wn4f[(size_t)kq * 256 + j];
                F4H8 xx; xx.f4 = x4[kq];
                a0 = __builtin_amdgcn_fdot2(w.h2[0], xx.h2[0], a0, false);
                a1 = __builtin_amdgcn_fdot2(w.h2[1], xx.h2[1], a1, false);
                a2 = __builtin_amdgcn_fdot2(w.h2[2], xx.h2[2], a2, false);
                a3 = __builtin_amdgcn_fdot2(w.h2[3], xx.h2[3], a3, false);
            }
            redNh[j] = (a0 + a1) + (a2 + a3);
        }
        __syncthreads();
        { // C: scores; 8 float4 loads, 32 h per thread
            int l2 = tid & 127, hg = tid >> 7;
            const float4* Tb = T4f + (size_t)(hg * 8) * 128 + l2;
            float s0 = 0.f, s1 = 0.f;
            #pragma unroll
            for (int i = 0; i < 8; ++i) {
                F4H8 tv4; tv4.f4 = Tb[(size_t)i * 128];
                #pragma unroll
                for (int c = 0; c < 4; ++c) {
                    int h = (hg * 8 + i) * 4 + c;
                    float2 tv = tqv[h];
                    float vv = vls[h];
                    float T0 = (float)tv4.h2[c].x, T1 = (float)tv4.h2[c].y;
                    float d0 = fmaxf(fmaf(T0, tv.x, 1.f), 1e-6f);
                    float d1 = fmaxf(fmaf(T1, tv.x, 1.f), 1e-6f);
                    s0 = fmaf(fmaf(vv, T0, tv.y), rcp_(d0), s0);
                    s1 = fmaf(fmaf(vv, T1, tv.y), rcp_(d1), s1);
                }
            }
            redBig[hg * 256 + 2 * l2] = s0;
            redBig[hg * 256 + 2 * l2 + 1] = s1;
        }
        __syncthreads();
        float sv = 0.f;
        if (tid < 256) { // D1: reduce score partials + wave max
            #pragma unroll
            for (int hg = 0; hg < 8; ++hg) sv += redBig[hg * 256 + tid];
            float m = sv;
            #pragma unroll
            for (int o = 1; o < 64; o <<= 1) m = fmaxf(m, __shfl_xor(m, o, 64));
            if ((tid & 63) == 0) wred[tid >> 6] = m;
        }
        __syncthreads();
        if (tid < 256) { // D2: exp(s - max) in fp16 + wave sum
            float mx = fmaxf(fmaxf(wred[0], wred[1]), fmaxf(wred[2], wred[3]));
            float e = __expf(sv - mx);
            attnH[tid] = __float2half(e);
            float s = e;
            #pragma unroll
            for (int o = 1; o < 64; o <<= 1) s += __shfl_xor(s, o, 64);
            if ((tid & 63) == 0) wred[4 + (tid >> 6)] = s;
        }
        __syncthreads();
        if (tid < 768) { // E': gateC[j] = sum_l attn[l] * P[l][j]; 32 float4 loads
            float a0 = 0.f, a1 = 0.f;
            #pragma unroll 8
            for (int lq = 0; lq < 32; ++lq) {
                F4H8 p; p.f4 = P4f[(size_t)lq * 768 + tid];
                F4H8 aa; aa.f4 = at4[lq];
                a0 = __builtin_amdgcn_fdot2(p.h2[0], aa.h2[0], a0, false);
                a1 = __builtin_amdgcn_fdot2(p.h2[1], aa.h2[1], a1, false);
                a0 = __builtin_amdgcn_fdot2(p.h2[2], aa.h2[2], a0, false);
                a1 = __builtin_amdgcn_fdot2(p.h2[3], aa.h2[3], a1, false);
            }
            gateC[tid] = a0 + a1;
        }
        __syncthreads();
        if (tid < 256) { // H: gate + GRU update (complete sums, prefetched gi)
            float rs = rcp_(wred[4] + wred[5] + wred[6] + wred[7]);
            float rr = redRZh[tid] + gateC[tid] * rs;
            float zz = redRZh[256 + tid] + gateC[256 + tid] * rs;
            float nh = redNh[tid];
            float nc = gateC[512 + tid] * rs;
            float r = sigm(gir + rr + bhhS[tid]);
            float z = sigm(giz + zz + bhhS[256 + tid]);
            float n = tanh_(gin + nc + r * (nh + bhhS[512 + tid]));
            float hk = hs[tid];
            float hn = (1.f - z) * n + z * hk;
            float hnew = (len < t) ? hk : hn;        // strict '<' per reference
            hs[tid] = hnew;
            if (t < len) csum += hnew;
            float other = __shfl_xor(hnew, 1, 64);
            if ((tid & 1) == 0) {
                f16x2 v = { (_Float16)hnew, (_Float16)other };
                x2[tid >> 1] = v;
            }
        }
        __syncthreads();
    }
    if (tid < 256) outp[8192 + b * HV + tid] = csum / (float)len;
}

extern "C" void kernel_launch(void* const* d_in, const int* in_sizes, int n_in,
                              void* d_out, int out_size, void* d_ws, size_t ws_size,
                              hipStream_t stream) {
    const int* anchor_input     = (const int*)d_in[0];
    const int* anchor_length    = (const int*)d_in[1];
    const int* candidate_input  = (const int*)d_in[2];
    const int* candidate_length = (const int*)d_in[3];
    const float* emb    = (const float*)d_in[5];
    const float* W_ih_a = (const float*)d_in[6];
    const float* W_hh_a = (const float*)d_in[7];
    const float* b_ih_a = (const float*)d_in[8];
    const float* b_hh_a = (const float*)d_in[9];
    const float* W_ih_c = (const float*)d_in[10];
    const float* W_hh_c = (const float*)d_in[11];
    const float* b_ih_c = (const float*)d_in[12];
    const float* b_hh_c = (const float*)d_in[13];
    const float* Wq     = (const float*)d_in[14];
    const float* Wk     = (const float*)d_in[15];
    const float* v_att  = (const float*)d_in[16];
    float* out = (float*)d_out;

    // workspace layout (float units), ~71.3 MB
    float* ws = (float*)d_ws;
    size_t off = 0;
    float* GI_a  = ws + off; off += (size_t)LAV * BB * G3;     // 6291456 (dead after anchor)
    float* GI_c  = ws + off; off += (size_t)LCV * BB * G3;     // 6291456
    float* AO    = ws + off; off += (size_t)BB * LAV * HV;     // 2097152
    float* hid   = ws + off; off += (size_t)BB * HV;           // 8192
    float* WT_a  = ws + off; off += 300 * 768;                 // 230400
    float* WT_cx = ws + off; off += 300 * 768;                 // 230400
    __half* T4H   = (__half*)(ws + off); off += (size_t)BB * HV * LAV / 2;  // quad pack
    __half* AOH   = (__half*)(ws + off); off += (size_t)BB * LAV * HV / 2;  // [b][l][h] pairs
    __half* WhaRH = (__half*)(ws + off); off += 98304 / 2;
    __half* WhaSH = (__half*)(ws + off); off += 98304 / 2;
    __half* Wq4   = (__half*)(ws + off); off += 65536 / 2;
    __half* Wrz4  = (__half*)(ws + off); off += 131072 / 2;
    __half* Wn4   = (__half*)(ws + off); off += 65536 / 2;
    float* WcxCT  = ws + off; off += 256 * 768;                // 196608
    // P4 [1024 lq][768][4 c] half = 12.6 MB, aliased onto GI_a (dead once anchor finishes)
    __half* P4H = (__half*)GI_a;

    prep_pack<<<dim3(900, 8), 256, 0, stream>>>(W_ih_a, W_ih_c, W_hh_a, W_hh_c, Wq,
                                                WT_a, WT_cx, WhaRH, WhaSH, Wq4, Wrz4, Wn4, WcxCT);
    gemm_tile<0><<<dim3(128, 12), 256, 0, stream>>>(emb, anchor_input, DV, WT_a, DV, G3, b_ih_a, GI_a);
    gemm_tile<0><<<dim3(128, 12), 256, 0, stream>>>(emb, candidate_input, DV, WT_cx, DV, G3, b_ih_c, GI_c);
    anchor_rnn<<<32, 768, 0, stream>>>(GI_a, anchor_length, b_hh_a, WhaRH, WhaSH, AO, AOH, hid, out);
    gemm_tile<1><<<dim3(128, 4), 256, 0, stream>>>(AO, nullptr, HV, Wk, HV, HV, nullptr, (float*)T4H);
    // P = AO @ W_ih_c[:,300:]^T  -> quad pack (writes over dead GI_a)
    gemm_tile<2><<<dim3(128, 12), 256, 0, stream>>>(AO, nullptr, HV, WcxCT, HV, G3, nullptr, (float*)P4H);
    cand_rnn<<<32, 1024, 0, stream>>>(GI_c, candidate_length, b_hh_c, Wrz4, Wn4, Wq4,
                                      v_att, P4H, T4H, hid, out);
}